// Round 1
// baseline (639.960 us; speedup 1.0000x reference)
//
#include <hip/hip_runtime.h>
#include <math.h>

#define NPTS 4096
#define KNB  50
#define WGRID 64

// ---------------- device scratch (written every launch before read) ----------------
__device__ int   g_idx[NPTS * KNB];
__device__ float g_dt[NPTS * KNB * 2];
__device__ float g_nrm[NPTS * 3];
__device__ float g_t1[NPTS * 3];
__device__ float g_t2[NPTS * 3];
__device__ float g_bmin[NPTS * 2];
__device__ float g_ml[NPTS];
__device__ float g_va[NPTS];
__device__ float g_terms[NPTS];

// ---------------- LAPACK-faithful helpers (fp32, branch-structure identical) -------
__device__ __forceinline__ float slapy2f(float x, float y) {
  float ax = fabsf(x), ay = fabsf(y);
  float w = fmaxf(ax, ay), z = fminf(ax, ay);
  if (z == 0.0f) return w;
  float t = z / w;
  return w * sqrtf(1.0f + t * t);
}

// LAPACK >= 3.10 slartg (c >= 0 convention)
__device__ __forceinline__ void slartgf(float f, float g, float* cs, float* sn, float* r) {
  const float safmin = 1.1754944e-38f;
  const float safmax = 8.5070592e+37f;
  const float rtmin = 1.0842022e-19f;   // sqrt(safmin)
  const float rtmax = 6.5219496e+18f;   // sqrt(safmax/2)
  if (g == 0.0f) {
    *cs = 1.0f; *sn = 0.0f; *r = f;
  } else if (f == 0.0f) {
    *cs = 0.0f; *sn = copysignf(1.0f, g); *r = fabsf(g);
  } else {
    float f1 = fabsf(f), g1 = fabsf(g);
    if (f1 > rtmin && f1 < rtmax && g1 > rtmin && g1 < rtmax) {
      float d = sqrtf(f * f + g * g);
      float p = 1.0f / d;
      *cs = f1 * p;
      *sn = g * copysignf(p, f);
      *r = copysignf(d, f);
    } else {
      float u = fminf(safmax, fmaxf(safmin, fmaxf(f1, g1)));
      float fs = f / u, gs = g / u;
      float d = sqrtf(fs * fs + gs * gs);
      float p = 1.0f / d;
      *cs = fabsf(fs) * p;
      *sn = gs * copysignf(p, f);
      *r = copysignf(d, f) * u;
    }
  }
}

__device__ void slaev2f(float a, float b, float c, float* rt1, float* rt2,
                        float* cs1, float* sn1) {
  float sm = a + c;
  float df = a - c;
  float adf = fabsf(df);
  float tb = b + b;
  float ab = fabsf(tb);
  float acmx, acmn;
  if (fabsf(a) > fabsf(c)) { acmx = a; acmn = c; } else { acmx = c; acmn = a; }
  float rt;
  if (adf > ab)      { float t = ab / adf; rt = adf * sqrtf(1.0f + t * t); }
  else if (adf < ab) { float t = adf / ab; rt = ab * sqrtf(1.0f + t * t); }
  else               { rt = ab * sqrtf(2.0f); }
  int sgn1;
  if (sm < 0.0f) {
    *rt1 = 0.5f * (sm - rt); sgn1 = -1;
    *rt2 = (acmx / *rt1) * acmn - (b / *rt1) * b;
  } else if (sm > 0.0f) {
    *rt1 = 0.5f * (sm + rt); sgn1 = 1;
    *rt2 = (acmx / *rt1) * acmn - (b / *rt1) * b;
  } else {
    *rt1 = 0.5f * rt; *rt2 = -0.5f * rt; sgn1 = 1;
  }
  float cs; int sgn2;
  if (df >= 0.0f) { cs = df + rt; sgn2 = 1; }
  else            { cs = df - rt; sgn2 = -1; }
  float acs = fabsf(cs);
  if (acs > ab) {
    float ct = -tb / cs;
    *sn1 = 1.0f / sqrtf(1.0f + ct * ct);
    *cs1 = ct * (*sn1);
  } else {
    if (ab == 0.0f) { *cs1 = 1.0f; *sn1 = 0.0f; }
    else {
      float tn = -cs / tb;
      *cs1 = 1.0f / sqrtf(1.0f + tn * tn);
      *sn1 = tn * (*cs1);
    }
  }
  if (sgn1 == sgn2) { float tn = *cs1; *cs1 = -(*sn1); *sn1 = tn; }
}

// ssteqr, n=3, COMPZ='I'. d[3], e[2] in; d sorted ascending out; Z columns = eigenvectors.
__device__ void ssteqr3(float* d, float* e, float Z[3][3]) {
  const float eps = 5.9604645e-08f;       // 2^-24
  const float eps2 = 3.5527137e-15f;      // eps^2
  const float safmin = 1.1754944e-38f;
  const float ssfmax = 3.0744574e+18f;    // sqrt(1/safmin)/3
  const float ssfmin = 3.0517578e-05f;    // sqrt(safmin)/eps2
  const int n = 3, nmaxit = 90;
  int jtot = 0;
  for (int r = 0; r < 3; ++r)
    for (int c = 0; c < 3; ++c) Z[r][c] = (r == c) ? 1.0f : 0.0f;

  int l1 = 1;
  while (l1 <= n) {
    if (l1 > 1) e[l1 - 2] = 0.0f;
    int m = n;
    for (int mm = l1; mm <= n - 1; ++mm) {
      float tst = fabsf(e[mm - 1]);
      if (tst == 0.0f) { m = mm; break; }
      if (tst <= (sqrtf(fabsf(d[mm - 1])) * sqrtf(fabsf(d[mm]))) * eps) {
        e[mm - 1] = 0.0f; m = mm; break;
      }
    }
    int l = l1, lsv = l1, lend = m, lendsv = m;
    l1 = m + 1;
    if (lend == l) continue;

    float anorm = 0.0f;
    for (int ii = l; ii <= lend; ++ii) anorm = fmaxf(anorm, fabsf(d[ii - 1]));
    for (int ii = l; ii <= lend - 1; ++ii) anorm = fmaxf(anorm, fabsf(e[ii - 1]));
    if (anorm == 0.0f) continue;
    int iscale = 0;
    if (anorm > ssfmax) {
      iscale = 1; float mul = ssfmax / anorm;
      for (int ii = l; ii <= lend; ++ii) d[ii - 1] *= mul;
      for (int ii = l; ii <= lend - 1; ++ii) e[ii - 1] *= mul;
    } else if (anorm < ssfmin) {
      iscale = 2; float mul = ssfmin / anorm;
      for (int ii = l; ii <= lend; ++ii) d[ii - 1] *= mul;
      for (int ii = l; ii <= lend - 1; ++ii) e[ii - 1] *= mul;
    }
    if (fabsf(d[lend - 1]) < fabsf(d[l - 1])) { lend = lsv; l = lendsv; }

    if (lend > l) {
      // ---- QL iteration ----
      for (;;) {
        int mm = lend;
        if (l != lend) {
          for (int t = l; t <= lend - 1; ++t) {
            float tst = e[t - 1] * e[t - 1];
            if (tst <= (eps2 * fabsf(d[t - 1])) * fabsf(d[t]) + safmin) { mm = t; break; }
          }
        }
        if (mm < lend) e[mm - 1] = 0.0f;
        float p = d[l - 1];
        if (mm == l) {                       // 1x1 deflation
          d[l - 1] = p; ++l;
          if (l <= lend) continue; break;
        }
        if (mm == l + 1) {                   // 2x2 via slaev2
          float rt1, rt2, c, s;
          slaev2f(d[l - 1], e[l - 1], d[l], &rt1, &rt2, &c, &s);
          for (int r = 0; r < 3; ++r) {
            float t = Z[r][l];
            Z[r][l]     = c * t - s * Z[r][l - 1];
            Z[r][l - 1] = s * t + c * Z[r][l - 1];
          }
          d[l - 1] = rt1; d[l] = rt2; e[l - 1] = 0.0f;
          l += 2;
          if (l <= lend) continue; break;
        }
        if (jtot == nmaxit) break;
        ++jtot;
        float g = (d[l] - p) / (2.0f * e[l - 1]);
        float r = slapy2f(g, 1.0f);
        g = d[mm - 1] - p + e[l - 1] / (g + copysignf(r, g));
        float s = 1.0f, c = 1.0f;
        p = 0.0f;
        float cw[2], sw[2];
        for (int i = mm - 1; i >= l; --i) {
          float f = s * e[i - 1];
          float b = c * e[i - 1];
          slartgf(g, f, &c, &s, &r);
          if (i != mm - 1) e[i] = r;
          g = d[i] - p;
          r = (d[i - 1] - g) * s + 2.0f * c * b;
          p = s * r;
          d[i] = g + p;
          g = c * r - b;
          cw[i - l] = c; sw[i - l] = -s;
        }
        for (int j = mm - 1; j >= l; --j) {  // slasr 'R','V','B'
          float cc = cw[j - l], ss = sw[j - l];
          for (int r2 = 0; r2 < 3; ++r2) {
            float t = Z[r2][j];
            Z[r2][j]     = cc * t - ss * Z[r2][j - 1];
            Z[r2][j - 1] = ss * t + cc * Z[r2][j - 1];
          }
        }
        d[l - 1] -= p;
        e[l - 1] = g;
      }
    } else {
      // ---- QR iteration ----
      for (;;) {
        int mm = lend;
        if (l != lend) {
          for (int t = l; t >= lend + 1; --t) {
            float tst = e[t - 2] * e[t - 2];
            if (tst <= (eps2 * fabsf(d[t - 1])) * fabsf(d[t - 2]) + safmin) { mm = t; break; }
          }
        }
        if (mm > lend) e[mm - 2] = 0.0f;
        float p = d[l - 1];
        if (mm == l) {
          d[l - 1] = p; --l;
          if (l >= lend) continue; break;
        }
        if (mm == l - 1) {
          float rt1, rt2, c, s;
          slaev2f(d[l - 2], e[l - 2], d[l - 1], &rt1, &rt2, &c, &s);
          for (int r2 = 0; r2 < 3; ++r2) {
            float t = Z[r2][l - 1];
            Z[r2][l - 1] = c * t - s * Z[r2][l - 2];
            Z[r2][l - 2] = s * t + c * Z[r2][l - 2];
          }
          d[l - 2] = rt1; d[l - 1] = rt2; e[l - 2] = 0.0f;
          l -= 2;
          if (l >= lend) continue; break;
        }
        if (jtot == nmaxit) break;
        ++jtot;
        float g = (d[l - 2] - p) / (2.0f * e[l - 2]);
        float r = slapy2f(g, 1.0f);
        g = d[mm - 1] - p + e[l - 2] / (g + copysignf(r, g));
        float s = 1.0f, c = 1.0f;
        p = 0.0f;
        float cw[2], sw[2];
        for (int i = mm; i <= l - 1; ++i) {
          float f = s * e[i - 1];
          float b = c * e[i - 1];
          slartgf(g, f, &c, &s, &r);
          if (i != mm) e[i - 2] = r;
          g = d[i - 1] - p;
          r = (d[i] - g) * s + 2.0f * c * b;
          p = s * r;
          d[i - 1] = g + p;
          g = c * r - b;
          cw[i - mm] = c; sw[i - mm] = s;
        }
        for (int j = mm; j <= l - 1; ++j) {  // slasr 'R','V','F'
          float cc = cw[j - mm], ss = sw[j - mm];
          for (int r2 = 0; r2 < 3; ++r2) {
            float t = Z[r2][j];
            Z[r2][j]     = cc * t - ss * Z[r2][j - 1];
            Z[r2][j - 1] = ss * t + cc * Z[r2][j - 1];
          }
        }
        d[l - 1] -= p;
        e[l - 2] = g;
      }
    }
    if (iscale == 1) {
      float mul = anorm / ssfmax;
      for (int ii = lsv; ii <= lendsv; ++ii) d[ii - 1] *= mul;
      for (int ii = lsv; ii <= lendsv - 1; ++ii) e[ii - 1] *= mul;
    } else if (iscale == 2) {
      float mul = anorm / ssfmin;
      for (int ii = lsv; ii <= lendsv; ++ii) d[ii - 1] *= mul;
      for (int ii = lsv; ii <= lendsv - 1; ++ii) e[ii - 1] *= mul;
    }
    if (jtot >= nmaxit) break;
  }
  // eigen-sort ascending (ssteqr selection sort; column swaps only)
  for (int ii = 2; ii <= n; ++ii) {
    int i0 = ii - 1, k0 = i0;
    float p = d[i0 - 1];
    for (int j = ii; j <= n; ++j)
      if (d[j - 1] < p) { k0 = j; p = d[j - 1]; }
    if (k0 != i0) {
      d[k0 - 1] = d[i0 - 1]; d[i0 - 1] = p;
      for (int r2 = 0; r2 < 3; ++r2) {
        float t = Z[r2][i0 - 1]; Z[r2][i0 - 1] = Z[r2][k0 - 1]; Z[r2][k0 - 1] = t;
      }
    }
  }
}

// ssytrd n=3 lower (one real Householder), LAPACK slarfg sign convention
__device__ void ssytrd3(float a11, float a21, float a31, float a22, float a32, float a33,
                        float d[3], float e[2], float* tau, float* u) {
  float xnorm = fabsf(a31);
  if (xnorm == 0.0f) {
    *tau = 0.0f; *u = 0.0f;
    d[0] = a11; d[1] = a22; d[2] = a33; e[0] = a21; e[1] = a32;
    return;
  }
  float beta = -copysignf(slapy2f(a21, xnorm), a21);
  float taui = (beta - a21) / beta;
  float uu = a31 * (1.0f / (a21 - beta));
  // w = taui * A2 * v, v=[1,uu]
  float w1 = taui * a22 + taui * (a32 * uu);
  float w2 = taui * a32 + (taui * uu) * a33;
  float alpha = -0.5f * taui * (w1 + w2 * uu);
  w1 += alpha; w2 += alpha * uu;
  float na22 = a22 - 2.0f * w1;
  float na32 = a32 - (uu * w1 + w2);
  float na33 = a33 - 2.0f * (uu * w2);
  d[0] = a11; d[1] = na22; d[2] = na33;
  e[0] = beta; e[1] = na32;
  *tau = taui; *u = uu;
}

// ---------------- K1: kNN (top-k ascending distance, ties -> lower index) ----------
__global__ __launch_bounds__(256) void knn_kernel(const float* __restrict__ pts, int N, int K) {
  __shared__ float sdist[NPTS];
  __shared__ float swv[4];
  __shared__ int swi[4];
  const int i = blockIdx.x;
  const float xi = pts[3 * i], yi = pts[3 * i + 1], zi = pts[3 * i + 2];
  const float d2i = xi * xi + yi * yi + zi * zi;
  for (int j = threadIdx.x; j < N; j += 256) {
    float xj = pts[3 * j], yj = pts[3 * j + 1], zj = pts[3 * j + 2];
    float d2j = xj * xj + yj * yj + zj * zj;
    float dot = fmaf(zi, zj, fmaf(yi, yj, xi * xj));
    sdist[j] = (d2i - 2.0f * dot) + d2j;
  }
  __syncthreads();
  const int lane = threadIdx.x & 63, wid = threadIdx.x >> 6;
  for (int sel = 0; sel < K; ++sel) {
    float bv = 3.0e38f; int bi = N;
    for (int j = threadIdx.x; j < N; j += 256) {
      float v = sdist[j];
      if (v < bv) { bv = v; bi = j; }     // ascending scan: strict < keeps lowest index
    }
    #pragma unroll
    for (int off = 32; off > 0; off >>= 1) {
      float ov = __shfl_down(bv, off);
      int oi = __shfl_down(bi, off);
      if (ov < bv || (ov == bv && oi < bi)) { bv = ov; bi = oi; }
    }
    if (lane == 0) { swv[wid] = bv; swi[wid] = bi; }
    __syncthreads();
    if (threadIdx.x == 0) {
      float fbv = swv[0]; int fbi = swi[0];
      for (int w = 1; w < 4; ++w)
        if (swv[w] < fbv || (swv[w] == fbv && swi[w] < fbi)) { fbv = swv[w]; fbi = swi[w]; }
      g_idx[i * KNB + sel] = fbi;
      sdist[fbi] = 3.0e38f;
    }
    __syncthreads();
  }
}

// ---------------- K2: frames (LAPACK-mimic 3x3 eigh), dt, bbox ---------------------
__global__ __launch_bounds__(256) void frames_kernel(const float* __restrict__ pts, int N, int K) {
  int i = blockIdx.x * 256 + threadIdx.x;
  if (i >= N) return;
  const int base = i * KNB;
  float mx = 0.0f, my = 0.0f, mz = 0.0f;
  for (int kk = 0; kk < KNB; ++kk) {
    int j = g_idx[base + kk];
    mx += pts[3 * j]; my += pts[3 * j + 1]; mz += pts[3 * j + 2];
  }
  mx /= 50.0f; my /= 50.0f; mz /= 50.0f;
  float c00 = 0, c01 = 0, c02 = 0, c11 = 0, c12 = 0, c22 = 0;
  for (int kk = 0; kk < KNB; ++kk) {
    int j = g_idx[base + kk];
    float cx = pts[3 * j] - mx, cy = pts[3 * j + 1] - my, cz = pts[3 * j + 2] - mz;
    c00 = fmaf(cx, cx, c00); c01 = fmaf(cx, cy, c01); c02 = fmaf(cx, cz, c02);
    c11 = fmaf(cy, cy, c11); c12 = fmaf(cy, cz, c12); c22 = fmaf(cz, cz, c22);
  }
  c00 *= 0.5f; c01 *= 0.5f; c02 *= 0.5f; c11 *= 0.5f; c12 *= 0.5f; c22 *= 0.5f;

  float d[3], e[2], tau, u;
  ssytrd3(c00, c01, c02, c11, c12, c22, d, e, &tau, &u);
  float Z[3][3];
  ssteqr3(d, e, Z);
  if (tau != 0.0f) {                       // sormtr: Z := H1 * Z (rows 1,2)
    for (int c = 0; c < 3; ++c) {
      float sum = Z[1][c] + u * Z[2][c];
      Z[1][c] -= tau * sum;
      Z[2][c] -= tau * u * sum;
    }
  }
  // frames rows = eigenvector columns (ascending eigenvalue)
  float n0 = Z[0][0], n1 = Z[1][0], n2 = Z[2][0];
  float a0 = Z[0][1], a1 = Z[1][1], a2 = Z[2][1];
  float b0 = Z[0][2], b1 = Z[1][2], b2 = Z[2][2];
  float cxp = a1 * b2 - a2 * b1, cyp = a2 * b0 - a0 * b2, czp = a0 * b1 - a1 * b0;
  float det = n0 * cxp + n1 * cyp + n2 * czp;
  a0 *= det; a1 *= det; a2 *= det;         // frames[:,1,:] *= det
  g_nrm[3 * i] = n0; g_nrm[3 * i + 1] = n1; g_nrm[3 * i + 2] = n2;
  g_t1[3 * i] = a0;  g_t1[3 * i + 1] = a1;  g_t1[3 * i + 2] = a2;
  g_t2[3 * i] = b0;  g_t2[3 * i + 1] = b1;  g_t2[3 * i + 2] = b2;

  const float xi = pts[3 * i], yi = pts[3 * i + 1], zi = pts[3 * i + 2];
  float mn0 = 3.0e38f, mx0 = -3.0e38f, mn1 = 3.0e38f, mx1 = -3.0e38f;
  for (int kk = 0; kk < KNB; ++kk) {
    int j = g_idx[base + kk];
    float dx = pts[3 * j] - xi, dy = pts[3 * j + 1] - yi, dz = pts[3 * j + 2] - zi;
    float dt0 = dx * a0 + dy * a1 + dz * a2;
    float dt1 = dx * b0 + dy * b1 + dz * b2;
    g_dt[2 * (base + kk)] = dt0;
    g_dt[2 * (base + kk) + 1] = dt1;
    mn0 = fminf(mn0, dt0); mx0 = fmaxf(mx0, dt0);
    mn1 = fminf(mn1, dt1); mx1 = fmaxf(mx1, dt1);
  }
  float bmin0 = mn0 * 1.1f, bmax0 = mx0 * 1.1f;
  float bmin1 = mn1 * 1.1f, bmax1 = mx1 * 1.1f;
  float ml = fmaxf(bmax0 - bmin0, bmax1 - bmin1);
  g_bmin[2 * i] = bmin0; g_bmin[2 * i + 1] = bmin1;
  g_ml[i] = ml;
}

// ---------------- K3: Voronoi cell-0 counts on 64x64 grid --------------------------
__global__ __launch_bounds__(256) void voronoi_kernel(int N, int K) {
  __shared__ float cxs[64], cys[64];
  __shared__ int swc[4];
  const int i = blockIdx.x;
  const float ml = g_ml[i];
  const float b0 = g_bmin[2 * i], b1 = g_bmin[2 * i + 1];
  if (threadIdx.x < KNB) {
    float dt0 = g_dt[2 * (i * KNB + threadIdx.x)];
    float dt1 = g_dt[2 * (i * KNB + threadIdx.x) + 1];
    cxs[threadIdx.x] = (dt0 - b0) / ml * 2.0f - 1.0f;
    cys[threadIdx.x] = (dt1 - b1) / ml * 2.0f - 1.0f;
  }
  __syncthreads();
  const float step = 2.0f / 63.0f;
  int cnt = 0;
  for (int g = threadIdx.x; g < WGRID * WGRID; g += 256) {
    int ix = g >> 6, iy = g & 63;
    float gx = fmaf((float)ix, step, -1.0f);
    float gy = fmaf((float)iy, step, -1.0f);
    float ex = gx - cxs[0], ey = gy - cys[0];
    float d0 = ex * ex + ey * ey;
    float m = 3.0e38f;
    #pragma unroll 7
    for (int jj = 1; jj < KNB; ++jj) {
      float dx = gx - cxs[jj], dy = gy - cys[jj];
      float dd = fmaf(dx, dx, dy * dy);
      m = fminf(m, dd);
    }
    cnt += (d0 <= m) ? 1 : 0;            // argmin==0 (first-index tie rule)
  }
  const int lane = threadIdx.x & 63, wid = threadIdx.x >> 6;
  #pragma unroll
  for (int off = 32; off > 0; off >>= 1) cnt += __shfl_down(cnt, off);
  if (lane == 0) swc[wid] = cnt;
  __syncthreads();
  if (threadIdx.x == 0) {
    int tot = swc[0] + swc[1] + swc[2] + swc[3];
    g_va[i] = (float)tot * (ml * ml) / 3969.0f;   // counts * max_len^2 / 63^2
  }
}

// ---------------- K4: Weingarten fit -> gaussian curvature * area ------------------
__global__ __launch_bounds__(256) void curv_kernel(int N, int K) {
  int i = blockIdx.x * 256 + threadIdx.x;
  if (i >= N) return;
  const int base = i * KNB;
  float nx = g_nrm[3 * i], ny = g_nrm[3 * i + 1], nz = g_nrm[3 * i + 2];
  float ax = g_t1[3 * i], ay = g_t1[3 * i + 1], az = g_t1[3 * i + 2];
  float bx = g_t2[3 * i], by = g_t2[3 * i + 1], bz = g_t2[3 * i + 2];
  float xx = 0, xy = 0, yy = 0;
  float y00 = 0, y01 = 0, y10 = 0, y11 = 0;
  for (int kk = 0; kk < KNB; ++kk) {
    int j = g_idx[base + kk];
    float dt0 = g_dt[2 * (base + kk)], dt1 = g_dt[2 * (base + kk) + 1];
    float lx = g_nrm[3 * j] - nx, ly = g_nrm[3 * j + 1] - ny, lz = g_nrm[3 * j + 2] - nz;
    float dn0 = lx * ax + ly * ay + lz * az;
    float dn1 = lx * bx + ly * by + lz * bz;
    xx = fmaf(dt0, dt0, xx); xy = fmaf(dt0, dt1, xy); yy = fmaf(dt1, dt1, yy);
    y00 = fmaf(dn0, dt0, y00); y01 = fmaf(dn0, dt1, y01);
    y10 = fmaf(dn1, dt0, y10); y11 = fmaf(dn1, dt1, y11);
  }
  float s00 = y00 + y00, s01 = y01 + y10, s11 = y11 + y11;
  // 2x2 eigh of XXT (sign-gauge irrelevant downstream; ascending order)
  float rt1, rt2, cs1, sn1;
  slaev2f(xx, xy, yy, &rt1, &rt2, &cs1, &sn1);
  float a, bb, q00, q10, q01, q11;
  if (rt1 <= rt2) { a = rt1; bb = rt2; q00 = cs1; q10 = sn1; q01 = -sn1; q11 = cs1; }
  else            { a = rt2; bb = rt1; q00 = -sn1; q10 = cs1; q01 = cs1; q11 = sn1; }
  // QTSQ = Q^T S Q
  float t00 = s00 * q00 + s01 * q10, t01 = s00 * q01 + s01 * q11;
  float t10 = s01 * q00 + s11 * q10, t11 = s01 * q01 + s11 * q11;
  float m00 = q00 * t00 + q10 * t10;
  float m01 = q00 * t01 + q10 * t11;
  float m10 = q01 * t00 + q11 * t10;
  float m11 = q01 * t01 + q11 * t11;
  float e00 = m00 / (2.0f * a + 1e-8f);
  float e01 = m01 / ((a + bb) + 1e-8f);
  float e10 = m10 / ((a + bb) + 1e-8f);
  float e11 = m11 / (2.0f * bb + 1e-8f);
  // Wmap = Q E Q^T
  float u00 = q00 * e00 + q01 * e10, u01 = q00 * e01 + q01 * e11;
  float u10 = q10 * e00 + q11 * e10, u11 = q10 * e01 + q11 * e11;
  float w00 = u00 * q00 + u01 * q01;
  float w01 = u00 * q10 + u01 * q11;
  float w10 = u10 * q00 + u11 * q01;
  float w11 = u10 * q10 + u11 * q11;
  float gauss = w00 * w11 - w01 * w10;
  g_terms[i] = gauss * g_va[i];
}

// ---------------- K5: final reduction ---------------------------------------------
__global__ __launch_bounds__(256) void reduce_kernel(float* __restrict__ out, int N) {
  __shared__ float sw[4];
  float s = 0.0f;
  for (int j = threadIdx.x; j < N; j += 256) s += g_terms[j];
  const int lane = threadIdx.x & 63, wid = threadIdx.x >> 6;
  #pragma unroll
  for (int off = 32; off > 0; off >>= 1) s += __shfl_down(s, off);
  if (lane == 0) sw[wid] = s;
  __syncthreads();
  if (threadIdx.x == 0) {
    float tot = sw[0] + sw[1] + sw[2] + sw[3];
    out[0] = (tot / 2.0f) / 3.14159265358979323846f;
  }
}

extern "C" void kernel_launch(void* const* d_in, const int* in_sizes, int n_in,
                              void* d_out, int out_size, void* d_ws, size_t ws_size,
                              hipStream_t stream) {
  const float* pts = (const float*)d_in[0];
  const int N = in_sizes[0] / 3;   // 4096
  const int K = KNB;
  knn_kernel<<<N, 256, 0, stream>>>(pts, N, K);
  frames_kernel<<<(N + 255) / 256, 256, 0, stream>>>(pts, N, K);
  voronoi_kernel<<<N, 256, 0, stream>>>(N, K);
  curv_kernel<<<(N + 255) / 256, 256, 0, stream>>>(N, K);
  reduce_kernel<<<1, 256, 0, stream>>>((float*)d_out, N);
}

// Round 2
// 226.674 us; speedup vs baseline: 2.8233x; 2.8233x over previous
//
#include <hip/hip_runtime.h>
#include <math.h>

#define NPTS 4096
#define KNB  50
#define WGRID 64

// ---------------- device scratch (written every launch before read) ----------------
__device__ int   g_idx[NPTS * KNB];
__device__ float g_dt[NPTS * KNB * 2];
__device__ float g_nrm[NPTS * 3];
__device__ float g_t1[NPTS * 3];
__device__ float g_t2[NPTS * 3];
__device__ float g_bmin[NPTS * 2];
__device__ float g_ml[NPTS];
__device__ float g_va[NPTS];
__device__ float g_terms[NPTS];

// ---------------- LAPACK-faithful helpers (fp32, branch-structure identical) -------
__device__ __forceinline__ float slapy2f(float x, float y) {
  float ax = fabsf(x), ay = fabsf(y);
  float w = fmaxf(ax, ay), z = fminf(ax, ay);
  if (z == 0.0f) return w;
  float t = z / w;
  return w * sqrtf(1.0f + t * t);
}

// LAPACK >= 3.10 slartg (c >= 0 convention)
__device__ __forceinline__ void slartgf(float f, float g, float* cs, float* sn, float* r) {
  const float safmin = 1.1754944e-38f;
  const float safmax = 8.5070592e+37f;
  const float rtmin = 1.0842022e-19f;   // sqrt(safmin)
  const float rtmax = 6.5219496e+18f;   // sqrt(safmax/2)
  if (g == 0.0f) {
    *cs = 1.0f; *sn = 0.0f; *r = f;
  } else if (f == 0.0f) {
    *cs = 0.0f; *sn = copysignf(1.0f, g); *r = fabsf(g);
  } else {
    float f1 = fabsf(f), g1 = fabsf(g);
    if (f1 > rtmin && f1 < rtmax && g1 > rtmin && g1 < rtmax) {
      float d = sqrtf(f * f + g * g);
      float p = 1.0f / d;
      *cs = f1 * p;
      *sn = g * copysignf(p, f);
      *r = copysignf(d, f);
    } else {
      float u = fminf(safmax, fmaxf(safmin, fmaxf(f1, g1)));
      float fs = f / u, gs = g / u;
      float d = sqrtf(fs * fs + gs * gs);
      float p = 1.0f / d;
      *cs = fabsf(fs) * p;
      *sn = gs * copysignf(p, f);
      *r = copysignf(d, f) * u;
    }
  }
}

__device__ void slaev2f(float a, float b, float c, float* rt1, float* rt2,
                        float* cs1, float* sn1) {
  float sm = a + c;
  float df = a - c;
  float adf = fabsf(df);
  float tb = b + b;
  float ab = fabsf(tb);
  float acmx, acmn;
  if (fabsf(a) > fabsf(c)) { acmx = a; acmn = c; } else { acmx = c; acmn = a; }
  float rt;
  if (adf > ab)      { float t = ab / adf; rt = adf * sqrtf(1.0f + t * t); }
  else if (adf < ab) { float t = adf / ab; rt = ab * sqrtf(1.0f + t * t); }
  else               { rt = ab * sqrtf(2.0f); }
  int sgn1;
  if (sm < 0.0f) {
    *rt1 = 0.5f * (sm - rt); sgn1 = -1;
    *rt2 = (acmx / *rt1) * acmn - (b / *rt1) * b;
  } else if (sm > 0.0f) {
    *rt1 = 0.5f * (sm + rt); sgn1 = 1;
    *rt2 = (acmx / *rt1) * acmn - (b / *rt1) * b;
  } else {
    *rt1 = 0.5f * rt; *rt2 = -0.5f * rt; sgn1 = 1;
  }
  float cs; int sgn2;
  if (df >= 0.0f) { cs = df + rt; sgn2 = 1; }
  else            { cs = df - rt; sgn2 = -1; }
  float acs = fabsf(cs);
  if (acs > ab) {
    float ct = -tb / cs;
    *sn1 = 1.0f / sqrtf(1.0f + ct * ct);
    *cs1 = ct * (*sn1);
  } else {
    if (ab == 0.0f) { *cs1 = 1.0f; *sn1 = 0.0f; }
    else {
      float tn = -cs / tb;
      *cs1 = 1.0f / sqrtf(1.0f + tn * tn);
      *sn1 = tn * (*cs1);
    }
  }
  if (sgn1 == sgn2) { float tn = *cs1; *cs1 = -(*sn1); *sn1 = tn; }
}

// ssteqr, n=3, COMPZ='I'. d[3], e[2] in; d sorted ascending out; Z columns = eigenvectors.
__device__ void ssteqr3(float* d, float* e, float Z[3][3]) {
  const float eps = 5.9604645e-08f;       // 2^-24
  const float eps2 = 3.5527137e-15f;      // eps^2
  const float safmin = 1.1754944e-38f;
  const float ssfmax = 3.0744574e+18f;    // sqrt(1/safmin)/3
  const float ssfmin = 3.0517578e-05f;    // sqrt(safmin)/eps2
  const int n = 3, nmaxit = 90;
  int jtot = 0;
  for (int r = 0; r < 3; ++r)
    for (int c = 0; c < 3; ++c) Z[r][c] = (r == c) ? 1.0f : 0.0f;

  int l1 = 1;
  while (l1 <= n) {
    if (l1 > 1) e[l1 - 2] = 0.0f;
    int m = n;
    for (int mm = l1; mm <= n - 1; ++mm) {
      float tst = fabsf(e[mm - 1]);
      if (tst == 0.0f) { m = mm; break; }
      if (tst <= (sqrtf(fabsf(d[mm - 1])) * sqrtf(fabsf(d[mm]))) * eps) {
        e[mm - 1] = 0.0f; m = mm; break;
      }
    }
    int l = l1, lsv = l1, lend = m, lendsv = m;
    l1 = m + 1;
    if (lend == l) continue;

    float anorm = 0.0f;
    for (int ii = l; ii <= lend; ++ii) anorm = fmaxf(anorm, fabsf(d[ii - 1]));
    for (int ii = l; ii <= lend - 1; ++ii) anorm = fmaxf(anorm, fabsf(e[ii - 1]));
    if (anorm == 0.0f) continue;
    int iscale = 0;
    if (anorm > ssfmax) {
      iscale = 1; float mul = ssfmax / anorm;
      for (int ii = l; ii <= lend; ++ii) d[ii - 1] *= mul;
      for (int ii = l; ii <= lend - 1; ++ii) e[ii - 1] *= mul;
    } else if (anorm < ssfmin) {
      iscale = 2; float mul = ssfmin / anorm;
      for (int ii = l; ii <= lend; ++ii) d[ii - 1] *= mul;
      for (int ii = l; ii <= lend - 1; ++ii) e[ii - 1] *= mul;
    }
    if (fabsf(d[lend - 1]) < fabsf(d[l - 1])) { lend = lsv; l = lendsv; }

    if (lend > l) {
      // ---- QL iteration ----
      for (;;) {
        int mm = lend;
        if (l != lend) {
          for (int t = l; t <= lend - 1; ++t) {
            float tst = e[t - 1] * e[t - 1];
            if (tst <= (eps2 * fabsf(d[t - 1])) * fabsf(d[t]) + safmin) { mm = t; break; }
          }
        }
        if (mm < lend) e[mm - 1] = 0.0f;
        float p = d[l - 1];
        if (mm == l) {                       // 1x1 deflation
          d[l - 1] = p; ++l;
          if (l <= lend) continue; break;
        }
        if (mm == l + 1) {                   // 2x2 via slaev2
          float rt1, rt2, c, s;
          slaev2f(d[l - 1], e[l - 1], d[l], &rt1, &rt2, &c, &s);
          for (int r = 0; r < 3; ++r) {
            float t = Z[r][l];
            Z[r][l]     = c * t - s * Z[r][l - 1];
            Z[r][l - 1] = s * t + c * Z[r][l - 1];
          }
          d[l - 1] = rt1; d[l] = rt2; e[l - 1] = 0.0f;
          l += 2;
          if (l <= lend) continue; break;
        }
        if (jtot == nmaxit) break;
        ++jtot;
        float g = (d[l] - p) / (2.0f * e[l - 1]);
        float r = slapy2f(g, 1.0f);
        g = d[mm - 1] - p + e[l - 1] / (g + copysignf(r, g));
        float s = 1.0f, c = 1.0f;
        p = 0.0f;
        float cw[2], sw[2];
        for (int i = mm - 1; i >= l; --i) {
          float f = s * e[i - 1];
          float b = c * e[i - 1];
          slartgf(g, f, &c, &s, &r);
          if (i != mm - 1) e[i] = r;
          g = d[i] - p;
          r = (d[i - 1] - g) * s + 2.0f * c * b;
          p = s * r;
          d[i] = g + p;
          g = c * r - b;
          cw[i - l] = c; sw[i - l] = -s;
        }
        for (int j = mm - 1; j >= l; --j) {  // slasr 'R','V','B'
          float cc = cw[j - l], ss = sw[j - l];
          for (int r2 = 0; r2 < 3; ++r2) {
            float t = Z[r2][j];
            Z[r2][j]     = cc * t - ss * Z[r2][j - 1];
            Z[r2][j - 1] = ss * t + cc * Z[r2][j - 1];
          }
        }
        d[l - 1] -= p;
        e[l - 1] = g;
      }
    } else {
      // ---- QR iteration ----
      for (;;) {
        int mm = lend;
        if (l != lend) {
          for (int t = l; t >= lend + 1; --t) {
            float tst = e[t - 2] * e[t - 2];
            if (tst <= (eps2 * fabsf(d[t - 1])) * fabsf(d[t - 2]) + safmin) { mm = t; break; }
          }
        }
        if (mm > lend) e[mm - 2] = 0.0f;
        float p = d[l - 1];
        if (mm == l) {
          d[l - 1] = p; --l;
          if (l >= lend) continue; break;
        }
        if (mm == l - 1) {
          float rt1, rt2, c, s;
          slaev2f(d[l - 2], e[l - 2], d[l - 1], &rt1, &rt2, &c, &s);
          for (int r2 = 0; r2 < 3; ++r2) {
            float t = Z[r2][l - 1];
            Z[r2][l - 1] = c * t - s * Z[r2][l - 2];
            Z[r2][l - 2] = s * t + c * Z[r2][l - 2];
          }
          d[l - 2] = rt1; d[l - 1] = rt2; e[l - 2] = 0.0f;
          l -= 2;
          if (l >= lend) continue; break;
        }
        if (jtot == nmaxit) break;
        ++jtot;
        float g = (d[l - 2] - p) / (2.0f * e[l - 2]);
        float r = slapy2f(g, 1.0f);
        g = d[mm - 1] - p + e[l - 2] / (g + copysignf(r, g));
        float s = 1.0f, c = 1.0f;
        p = 0.0f;
        float cw[2], sw[2];
        for (int i = mm; i <= l - 1; ++i) {
          float f = s * e[i - 1];
          float b = c * e[i - 1];
          slartgf(g, f, &c, &s, &r);
          if (i != mm) e[i - 2] = r;
          g = d[i - 1] - p;
          r = (d[i] - g) * s + 2.0f * c * b;
          p = s * r;
          d[i - 1] = g + p;
          g = c * r - b;
          cw[i - mm] = c; sw[i - mm] = s;
        }
        for (int j = mm; j <= l - 1; ++j) {  // slasr 'R','V','F'
          float cc = cw[j - mm], ss = sw[j - mm];
          for (int r2 = 0; r2 < 3; ++r2) {
            float t = Z[r2][j];
            Z[r2][j]     = cc * t - ss * Z[r2][j - 1];
            Z[r2][j - 1] = ss * t + cc * Z[r2][j - 1];
          }
        }
        d[l - 1] -= p;
        e[l - 2] = g;
      }
    }
    if (iscale == 1) {
      float mul = anorm / ssfmax;
      for (int ii = lsv; ii <= lendsv; ++ii) d[ii - 1] *= mul;
      for (int ii = lsv; ii <= lendsv - 1; ++ii) e[ii - 1] *= mul;
    } else if (iscale == 2) {
      float mul = anorm / ssfmin;
      for (int ii = lsv; ii <= lendsv; ++ii) d[ii - 1] *= mul;
      for (int ii = lsv; ii <= lendsv - 1; ++ii) e[ii - 1] *= mul;
    }
    if (jtot >= nmaxit) break;
  }
  // eigen-sort ascending (ssteqr selection sort; column swaps only)
  for (int ii = 2; ii <= n; ++ii) {
    int i0 = ii - 1, k0 = i0;
    float p = d[i0 - 1];
    for (int j = ii; j <= n; ++j)
      if (d[j - 1] < p) { k0 = j; p = d[j - 1]; }
    if (k0 != i0) {
      d[k0 - 1] = d[i0 - 1]; d[i0 - 1] = p;
      for (int r2 = 0; r2 < 3; ++r2) {
        float t = Z[r2][i0 - 1]; Z[r2][i0 - 1] = Z[r2][k0 - 1]; Z[r2][k0 - 1] = t;
      }
    }
  }
}

// ssytrd n=3 lower (one real Householder), LAPACK slarfg sign convention
__device__ void ssytrd3(float a11, float a21, float a31, float a22, float a32, float a33,
                        float d[3], float e[2], float* tau, float* u) {
  float xnorm = fabsf(a31);
  if (xnorm == 0.0f) {
    *tau = 0.0f; *u = 0.0f;
    d[0] = a11; d[1] = a22; d[2] = a33; e[0] = a21; e[1] = a32;
    return;
  }
  float beta = -copysignf(slapy2f(a21, xnorm), a21);
  float taui = (beta - a21) / beta;
  float uu = a31 * (1.0f / (a21 - beta));
  float w1 = taui * a22 + taui * (a32 * uu);
  float w2 = taui * a32 + (taui * uu) * a33;
  float alpha = -0.5f * taui * (w1 + w2 * uu);
  w1 += alpha; w2 += alpha * uu;
  float na22 = a22 - 2.0f * w1;
  float na32 = a32 - (uu * w1 + w2);
  float na33 = a33 - 2.0f * (uu * w2);
  d[0] = a11; d[1] = na22; d[2] = na33;
  e[0] = beta; e[1] = na32;
  *tau = taui; *u = uu;
}

// ---------------- K1: kNN via radix-select (rank-49 threshold) ---------------------
// Selects the identical (value, index)-ordered top-50 set as sequential argmin.
// Slot 0 = self point (guaranteed global min); slots 1..49 unordered (downstream
// reductions are order-invariant).
__global__ __launch_bounds__(256) void knn_kernel(const float* __restrict__ pts, int N) {
  __shared__ unsigned skey[NPTS];      // 16 KB: order-preserving uint keys
  __shared__ unsigned hist[256];
  __shared__ unsigned sred[4];
  __shared__ unsigned sbin[2];
  __shared__ int eqlist[64];
  __shared__ unsigned counters[2];
  const int i = blockIdx.x;
  const int tid = threadIdx.x;
  const float xi = pts[3 * i], yi = pts[3 * i + 1], zi = pts[3 * i + 2];
  const float d2i = xi * xi + yi * yi + zi * zi;
  for (int j = tid; j < N; j += 256) {
    float xj = pts[3 * j], yj = pts[3 * j + 1], zj = pts[3 * j + 2];
    float d2j = xj * xj + yj * yj + zj * zj;
    float dot = fmaf(zi, zj, fmaf(yi, yj, xi * xj));
    float dist = (d2i - 2.0f * dot) + d2j;     // identical formula to R1
    unsigned u = __float_as_uint(dist);
    u = (u & 0x80000000u) ? ~u : (u | 0x80000000u);  // ascending-order bijection
    skey[j] = u;
  }
  const int lane = tid & 63, wid = tid >> 6;
  unsigned prefix = 0;
  unsigned rank = 49;                          // 0-indexed rank of the 50th smallest
  for (int pass = 0; pass < 4; ++pass) {
    const int shift = 24 - 8 * pass;
    hist[tid] = 0;
    __syncthreads();
    const unsigned hmask = (pass == 0) ? 0u : (0xFFFFFFFFu << (shift + 8));
    for (int j = tid; j < N; j += 256) {
      unsigned u = skey[j];
      if (((u ^ prefix) & hmask) == 0)
        atomicAdd(&hist[(u >> shift) & 255u], 1u);
    }
    __syncthreads();
    unsigned h = hist[tid];
    unsigned c = h;
    #pragma unroll
    for (int off = 1; off < 64; off <<= 1) {
      unsigned o = __shfl_up(c, off);
      if (lane >= off) c += o;
    }
    if (lane == 63) sred[wid] = c;
    __syncthreads();
    unsigned wbase = 0;
    for (int w = 0; w < wid; ++w) wbase += sred[w];
    c += wbase;
    unsigned excl = c - h;
    if (rank >= excl && rank < c) { sbin[0] = (unsigned)tid; sbin[1] = rank - excl; }
    __syncthreads();
    prefix |= sbin[0] << shift;
    rank = sbin[1];
  }
  const unsigned T = prefix;                   // exact key of rank-49 element
  if (tid == 0) { counters[0] = 1; counters[1] = 0; }
  __syncthreads();
  for (int j = tid; j < N; j += 256) {
    unsigned u = skey[j];
    if (u < T) {
      if (j != i) {
        unsigned s = atomicAdd(&counters[0], 1u);
        g_idx[i * KNB + s] = j;
      }
    } else if (u == T) {
      unsigned e = atomicAdd(&counters[1], 1u);
      if (e < 64u) eqlist[e] = j;
    }
  }
  __syncthreads();
  if (tid == 0) {
    g_idx[i * KNB] = i;                        // self = global min distance
    int slot = (int)counters[0];               // == count(key < T)
    int need = KNB - slot;                     // >= 1
    int ne = (int)counters[1]; if (ne > 64) ne = 64;
    for (int e = 0; e < need; ++e) {           // take lowest-index equals at T
      int bi = 0, bv = 0x7FFFFFFF;
      for (int q = 0; q < ne; ++q)
        if (eqlist[q] < bv) { bv = eqlist[q]; bi = q; }
      g_idx[i * KNB + slot + e] = bv;
      eqlist[bi] = 0x7FFFFFFF;
    }
  }
}

// ---------------- K2: frames (LAPACK-mimic 3x3 eigh), dt, bbox ---------------------
__global__ __launch_bounds__(64) void frames_kernel(const float* __restrict__ pts, int N) {
  int i = blockIdx.x * 64 + threadIdx.x;
  if (i >= N) return;
  const int base = i * KNB;
  float mx = 0.0f, my = 0.0f, mz = 0.0f;
  for (int kk = 0; kk < KNB; ++kk) {
    int j = g_idx[base + kk];
    mx += pts[3 * j]; my += pts[3 * j + 1]; mz += pts[3 * j + 2];
  }
  mx /= 50.0f; my /= 50.0f; mz /= 50.0f;
  float c00 = 0, c01 = 0, c02 = 0, c11 = 0, c12 = 0, c22 = 0;
  for (int kk = 0; kk < KNB; ++kk) {
    int j = g_idx[base + kk];
    float cx = pts[3 * j] - mx, cy = pts[3 * j + 1] - my, cz = pts[3 * j + 2] - mz;
    c00 = fmaf(cx, cx, c00); c01 = fmaf(cx, cy, c01); c02 = fmaf(cx, cz, c02);
    c11 = fmaf(cy, cy, c11); c12 = fmaf(cy, cz, c12); c22 = fmaf(cz, cz, c22);
  }
  c00 *= 0.5f; c01 *= 0.5f; c02 *= 0.5f; c11 *= 0.5f; c12 *= 0.5f; c22 *= 0.5f;

  float d[3], e[2], tau, u;
  ssytrd3(c00, c01, c02, c11, c12, c22, d, e, &tau, &u);
  float Z[3][3];
  ssteqr3(d, e, Z);
  if (tau != 0.0f) {                       // sormtr: Z := H1 * Z (rows 1,2)
    for (int c = 0; c < 3; ++c) {
      float sum = Z[1][c] + u * Z[2][c];
      Z[1][c] -= tau * sum;
      Z[2][c] -= tau * u * sum;
    }
  }
  float n0 = Z[0][0], n1 = Z[1][0], n2 = Z[2][0];
  float a0 = Z[0][1], a1 = Z[1][1], a2 = Z[2][1];
  float b0 = Z[0][2], b1 = Z[1][2], b2 = Z[2][2];
  float cxp = a1 * b2 - a2 * b1, cyp = a2 * b0 - a0 * b2, czp = a0 * b1 - a1 * b0;
  float det = n0 * cxp + n1 * cyp + n2 * czp;
  a0 *= det; a1 *= det; a2 *= det;         // frames[:,1,:] *= det
  g_nrm[3 * i] = n0; g_nrm[3 * i + 1] = n1; g_nrm[3 * i + 2] = n2;
  g_t1[3 * i] = a0;  g_t1[3 * i + 1] = a1;  g_t1[3 * i + 2] = a2;
  g_t2[3 * i] = b0;  g_t2[3 * i + 1] = b1;  g_t2[3 * i + 2] = b2;

  const float xi = pts[3 * i], yi = pts[3 * i + 1], zi = pts[3 * i + 2];
  float mn0 = 3.0e38f, mx0 = -3.0e38f, mn1 = 3.0e38f, mx1 = -3.0e38f;
  for (int kk = 0; kk < KNB; ++kk) {
    int j = g_idx[base + kk];
    float dx = pts[3 * j] - xi, dy = pts[3 * j + 1] - yi, dz = pts[3 * j + 2] - zi;
    float dt0 = dx * a0 + dy * a1 + dz * a2;
    float dt1 = dx * b0 + dy * b1 + dz * b2;
    g_dt[2 * (base + kk)] = dt0;
    g_dt[2 * (base + kk) + 1] = dt1;
    mn0 = fminf(mn0, dt0); mx0 = fmaxf(mx0, dt0);
    mn1 = fminf(mn1, dt1); mx1 = fmaxf(mx1, dt1);
  }
  float bmin0 = mn0 * 1.1f, bmax0 = mx0 * 1.1f;
  float bmin1 = mn1 * 1.1f, bmax1 = mx1 * 1.1f;
  float ml = fmaxf(bmax0 - bmin0, bmax1 - bmin1);
  g_bmin[2 * i] = bmin0; g_bmin[2 * i + 1] = bmin1;
  g_ml[i] = ml;
}

// ---------------- K3: Voronoi cell-0 counts, tiled + early exit --------------------
// Comparison math identical to R1: dd = fmaf(dx,dx,dy*dy); count iff d0 <= min(dd).
// Early exit when every lane's cell is already beaten (exists dd < d0).
__global__ __launch_bounds__(256) void voronoi_kernel(int N) {
  __shared__ float2 sc[KNB];
  __shared__ int swc[4];
  const int i = blockIdx.x;
  const int tid = threadIdx.x;
  const float ml = g_ml[i];
  const float b0 = g_bmin[2 * i], b1 = g_bmin[2 * i + 1];
  if (tid < KNB) {
    float dt0 = g_dt[2 * (i * KNB + tid)];
    float dt1 = g_dt[2 * (i * KNB + tid) + 1];
    sc[tid] = make_float2((dt0 - b0) / ml * 2.0f - 1.0f,
                          (dt1 - b1) / ml * 2.0f - 1.0f);
  }
  __syncthreads();
  const float step = 2.0f / 63.0f;
  const int lane = tid & 63, wid = tid >> 6;
  const int lx = lane & 7, ly = lane >> 3;
  const float c0x = sc[0].x, c0y = sc[0].y;
  int cnt = 0;
  for (int t = 0; t < 16; ++t) {
    int tile = t * 4 + wid;                  // 64 tiles of 8x8 cells
    int tx = tile & 7, ty = tile >> 3;
    int ix = tx * 8 + lx, iy = ty * 8 + ly;
    float gx = fmaf((float)ix, step, -1.0f);
    float gy = fmaf((float)iy, step, -1.0f);
    float ex = gx - c0x, ey = gy - c0y;
    float d0 = ex * ex + ey * ey;
    bool beaten = false;
    for (int jb = 1; jb < KNB; jb += 4) {
      #pragma unroll
      for (int u = 0; u < 4; ++u) {
        int j = jb + u;
        if (j < KNB) {
          float2 cc = sc[j];
          float dx = gx - cc.x, dy = gy - cc.y;
          float dd = fmaf(dx, dx, dy * dy);
          beaten = beaten || (dd < d0);
        }
      }
      if (__all(beaten)) break;
    }
    cnt += beaten ? 0 : 1;
  }
  #pragma unroll
  for (int off = 32; off > 0; off >>= 1) cnt += __shfl_down(cnt, off);
  if (lane == 0) swc[wid] = cnt;
  __syncthreads();
  if (tid == 0) {
    int tot = swc[0] + swc[1] + swc[2] + swc[3];
    g_va[i] = (float)tot * (ml * ml) / 3969.0f;
  }
}

// ---------------- K4: Weingarten fit -> gaussian curvature * area ------------------
__global__ __launch_bounds__(64) void curv_kernel(int N) {
  int i = blockIdx.x * 64 + threadIdx.x;
  if (i >= N) return;
  const int base = i * KNB;
  float nx = g_nrm[3 * i], ny = g_nrm[3 * i + 1], nz = g_nrm[3 * i + 2];
  float ax = g_t1[3 * i], ay = g_t1[3 * i + 1], az = g_t1[3 * i + 2];
  float bx = g_t2[3 * i], by = g_t2[3 * i + 1], bz = g_t2[3 * i + 2];
  float xx = 0, xy = 0, yy = 0;
  float y00 = 0, y01 = 0, y10 = 0, y11 = 0;
  for (int kk = 0; kk < KNB; ++kk) {
    int j = g_idx[base + kk];
    float dt0 = g_dt[2 * (base + kk)], dt1 = g_dt[2 * (base + kk) + 1];
    float lx = g_nrm[3 * j] - nx, ly = g_nrm[3 * j + 1] - ny, lz = g_nrm[3 * j + 2] - nz;
    float dn0 = lx * ax + ly * ay + lz * az;
    float dn1 = lx * bx + ly * by + lz * bz;
    xx = fmaf(dt0, dt0, xx); xy = fmaf(dt0, dt1, xy); yy = fmaf(dt1, dt1, yy);
    y00 = fmaf(dn0, dt0, y00); y01 = fmaf(dn0, dt1, y01);
    y10 = fmaf(dn1, dt0, y10); y11 = fmaf(dn1, dt1, y11);
  }
  float s00 = y00 + y00, s01 = y01 + y10, s11 = y11 + y11;
  float rt1, rt2, cs1, sn1;
  slaev2f(xx, xy, yy, &rt1, &rt2, &cs1, &sn1);
  float a, bb, q00, q10, q01, q11;
  if (rt1 <= rt2) { a = rt1; bb = rt2; q00 = cs1; q10 = sn1; q01 = -sn1; q11 = cs1; }
  else            { a = rt2; bb = rt1; q00 = -sn1; q10 = cs1; q01 = cs1; q11 = sn1; }
  float t00 = s00 * q00 + s01 * q10, t01 = s00 * q01 + s01 * q11;
  float t10 = s01 * q00 + s11 * q10, t11 = s01 * q01 + s11 * q11;
  float m00 = q00 * t00 + q10 * t10;
  float m01 = q00 * t01 + q10 * t11;
  float m10 = q01 * t00 + q11 * t10;
  float m11 = q01 * t01 + q11 * t11;
  float e00 = m00 / (2.0f * a + 1e-8f);
  float e01 = m01 / ((a + bb) + 1e-8f);
  float e10 = m10 / ((a + bb) + 1e-8f);
  float e11 = m11 / (2.0f * bb + 1e-8f);
  float u00 = q00 * e00 + q01 * e10, u01 = q00 * e01 + q01 * e11;
  float u10 = q10 * e00 + q11 * e10, u11 = q10 * e01 + q11 * e11;
  float w00 = u00 * q00 + u01 * q01;
  float w01 = u00 * q10 + u01 * q11;
  float w10 = u10 * q00 + u11 * q01;
  float w11 = u10 * q10 + u11 * q11;
  float gauss = w00 * w11 - w01 * w10;
  g_terms[i] = gauss * g_va[i];
}

// ---------------- K5: final reduction ---------------------------------------------
__global__ __launch_bounds__(256) void reduce_kernel(float* __restrict__ out, int N) {
  __shared__ float sw[4];
  float s = 0.0f;
  for (int j = threadIdx.x; j < N; j += 256) s += g_terms[j];
  const int lane = threadIdx.x & 63, wid = threadIdx.x >> 6;
  #pragma unroll
  for (int off = 32; off > 0; off >>= 1) s += __shfl_down(s, off);
  if (lane == 0) sw[wid] = s;
  __syncthreads();
  if (threadIdx.x == 0) {
    float tot = sw[0] + sw[1] + sw[2] + sw[3];
    out[0] = (tot / 2.0f) / 3.14159265358979323846f;
  }
}

extern "C" void kernel_launch(void* const* d_in, const int* in_sizes, int n_in,
                              void* d_out, int out_size, void* d_ws, size_t ws_size,
                              hipStream_t stream) {
  const float* pts = (const float*)d_in[0];
  const int N = in_sizes[0] / 3;   // 4096
  knn_kernel<<<N, 256, 0, stream>>>(pts, N);
  frames_kernel<<<(N + 63) / 64, 64, 0, stream>>>(pts, N);
  voronoi_kernel<<<N, 256, 0, stream>>>(N);
  curv_kernel<<<(N + 63) / 64, 64, 0, stream>>>(N);
  reduce_kernel<<<1, 256, 0, stream>>>((float*)d_out, N);
}

// Round 3
// 210.508 us; speedup vs baseline: 3.0401x; 1.0768x over previous
//
#include <hip/hip_runtime.h>
#include <math.h>

#define NPTS 4096
#define KNB  50
#define WGRID 64

// ---------------- device scratch (written every launch before read) ----------------
__device__ int   g_idx[NPTS * KNB];
__device__ float g_dt[NPTS * KNB * 2];
__device__ float g_nrm[NPTS * 3];
__device__ float g_t1[NPTS * 3];
__device__ float g_t2[NPTS * 3];
__device__ float g_bmin[NPTS * 2];
__device__ float g_ml[NPTS];
__device__ float g_va[NPTS];
__device__ float g_terms[NPTS];

// ---------------- LAPACK-faithful helpers (fp32, branch-structure identical) -------
__device__ __forceinline__ float slapy2f(float x, float y) {
  float ax = fabsf(x), ay = fabsf(y);
  float w = fmaxf(ax, ay), z = fminf(ax, ay);
  if (z == 0.0f) return w;
  float t = z / w;
  return w * sqrtf(1.0f + t * t);
}

// LAPACK >= 3.10 slartg (c >= 0 convention)
__device__ __forceinline__ void slartgf(float f, float g, float* cs, float* sn, float* r) {
  const float safmin = 1.1754944e-38f;
  const float safmax = 8.5070592e+37f;
  const float rtmin = 1.0842022e-19f;
  const float rtmax = 6.5219496e+18f;
  if (g == 0.0f) {
    *cs = 1.0f; *sn = 0.0f; *r = f;
  } else if (f == 0.0f) {
    *cs = 0.0f; *sn = copysignf(1.0f, g); *r = fabsf(g);
  } else {
    float f1 = fabsf(f), g1 = fabsf(g);
    if (f1 > rtmin && f1 < rtmax && g1 > rtmin && g1 < rtmax) {
      float d = sqrtf(f * f + g * g);
      float p = 1.0f / d;
      *cs = f1 * p;
      *sn = g * copysignf(p, f);
      *r = copysignf(d, f);
    } else {
      float u = fminf(safmax, fmaxf(safmin, fmaxf(f1, g1)));
      float fs = f / u, gs = g / u;
      float d = sqrtf(fs * fs + gs * gs);
      float p = 1.0f / d;
      *cs = fabsf(fs) * p;
      *sn = gs * copysignf(p, f);
      *r = copysignf(d, f) * u;
    }
  }
}

__device__ void slaev2f(float a, float b, float c, float* rt1, float* rt2,
                        float* cs1, float* sn1) {
  float sm = a + c;
  float df = a - c;
  float adf = fabsf(df);
  float tb = b + b;
  float ab = fabsf(tb);
  float acmx, acmn;
  if (fabsf(a) > fabsf(c)) { acmx = a; acmn = c; } else { acmx = c; acmn = a; }
  float rt;
  if (adf > ab)      { float t = ab / adf; rt = adf * sqrtf(1.0f + t * t); }
  else if (adf < ab) { float t = adf / ab; rt = ab * sqrtf(1.0f + t * t); }
  else               { rt = ab * sqrtf(2.0f); }
  int sgn1;
  if (sm < 0.0f) {
    *rt1 = 0.5f * (sm - rt); sgn1 = -1;
    *rt2 = (acmx / *rt1) * acmn - (b / *rt1) * b;
  } else if (sm > 0.0f) {
    *rt1 = 0.5f * (sm + rt); sgn1 = 1;
    *rt2 = (acmx / *rt1) * acmn - (b / *rt1) * b;
  } else {
    *rt1 = 0.5f * rt; *rt2 = -0.5f * rt; sgn1 = 1;
  }
  float cs; int sgn2;
  if (df >= 0.0f) { cs = df + rt; sgn2 = 1; }
  else            { cs = df - rt; sgn2 = -1; }
  float acs = fabsf(cs);
  if (acs > ab) {
    float ct = -tb / cs;
    *sn1 = 1.0f / sqrtf(1.0f + ct * ct);
    *cs1 = ct * (*sn1);
  } else {
    if (ab == 0.0f) { *cs1 = 1.0f; *sn1 = 0.0f; }
    else {
      float tn = -cs / tb;
      *cs1 = 1.0f / sqrtf(1.0f + tn * tn);
      *sn1 = tn * (*cs1);
    }
  }
  if (sgn1 == sgn2) { float tn = *cs1; *cs1 = -(*sn1); *sn1 = tn; }
}

// ssteqr, n=3, COMPZ='I'.
__device__ void ssteqr3(float* d, float* e, float Z[3][3]) {
  const float eps = 5.9604645e-08f;
  const float eps2 = 3.5527137e-15f;
  const float safmin = 1.1754944e-38f;
  const float ssfmax = 3.0744574e+18f;
  const float ssfmin = 3.0517578e-05f;
  const int n = 3, nmaxit = 90;
  int jtot = 0;
  for (int r = 0; r < 3; ++r)
    for (int c = 0; c < 3; ++c) Z[r][c] = (r == c) ? 1.0f : 0.0f;

  int l1 = 1;
  while (l1 <= n) {
    if (l1 > 1) e[l1 - 2] = 0.0f;
    int m = n;
    for (int mm = l1; mm <= n - 1; ++mm) {
      float tst = fabsf(e[mm - 1]);
      if (tst == 0.0f) { m = mm; break; }
      if (tst <= (sqrtf(fabsf(d[mm - 1])) * sqrtf(fabsf(d[mm]))) * eps) {
        e[mm - 1] = 0.0f; m = mm; break;
      }
    }
    int l = l1, lsv = l1, lend = m, lendsv = m;
    l1 = m + 1;
    if (lend == l) continue;

    float anorm = 0.0f;
    for (int ii = l; ii <= lend; ++ii) anorm = fmaxf(anorm, fabsf(d[ii - 1]));
    for (int ii = l; ii <= lend - 1; ++ii) anorm = fmaxf(anorm, fabsf(e[ii - 1]));
    if (anorm == 0.0f) continue;
    int iscale = 0;
    if (anorm > ssfmax) {
      iscale = 1; float mul = ssfmax / anorm;
      for (int ii = l; ii <= lend; ++ii) d[ii - 1] *= mul;
      for (int ii = l; ii <= lend - 1; ++ii) e[ii - 1] *= mul;
    } else if (anorm < ssfmin) {
      iscale = 2; float mul = ssfmin / anorm;
      for (int ii = l; ii <= lend; ++ii) d[ii - 1] *= mul;
      for (int ii = l; ii <= lend - 1; ++ii) e[ii - 1] *= mul;
    }
    if (fabsf(d[lend - 1]) < fabsf(d[l - 1])) { lend = lsv; l = lendsv; }

    if (lend > l) {
      for (;;) {
        int mm = lend;
        if (l != lend) {
          for (int t = l; t <= lend - 1; ++t) {
            float tst = e[t - 1] * e[t - 1];
            if (tst <= (eps2 * fabsf(d[t - 1])) * fabsf(d[t]) + safmin) { mm = t; break; }
          }
        }
        if (mm < lend) e[mm - 1] = 0.0f;
        float p = d[l - 1];
        if (mm == l) {
          d[l - 1] = p; ++l;
          if (l <= lend) continue; break;
        }
        if (mm == l + 1) {
          float rt1, rt2, c, s;
          slaev2f(d[l - 1], e[l - 1], d[l], &rt1, &rt2, &c, &s);
          for (int r = 0; r < 3; ++r) {
            float t = Z[r][l];
            Z[r][l]     = c * t - s * Z[r][l - 1];
            Z[r][l - 1] = s * t + c * Z[r][l - 1];
          }
          d[l - 1] = rt1; d[l] = rt2; e[l - 1] = 0.0f;
          l += 2;
          if (l <= lend) continue; break;
        }
        if (jtot == nmaxit) break;
        ++jtot;
        float g = (d[l] - p) / (2.0f * e[l - 1]);
        float r = slapy2f(g, 1.0f);
        g = d[mm - 1] - p + e[l - 1] / (g + copysignf(r, g));
        float s = 1.0f, c = 1.0f;
        p = 0.0f;
        float cw[2], sw[2];
        for (int i = mm - 1; i >= l; --i) {
          float f = s * e[i - 1];
          float b = c * e[i - 1];
          slartgf(g, f, &c, &s, &r);
          if (i != mm - 1) e[i] = r;
          g = d[i] - p;
          r = (d[i - 1] - g) * s + 2.0f * c * b;
          p = s * r;
          d[i] = g + p;
          g = c * r - b;
          cw[i - l] = c; sw[i - l] = -s;
        }
        for (int j = mm - 1; j >= l; --j) {
          float cc = cw[j - l], ss = sw[j - l];
          for (int r2 = 0; r2 < 3; ++r2) {
            float t = Z[r2][j];
            Z[r2][j]     = cc * t - ss * Z[r2][j - 1];
            Z[r2][j - 1] = ss * t + cc * Z[r2][j - 1];
          }
        }
        d[l - 1] -= p;
        e[l - 1] = g;
      }
    } else {
      for (;;) {
        int mm = lend;
        if (l != lend) {
          for (int t = l; t >= lend + 1; --t) {
            float tst = e[t - 2] * e[t - 2];
            if (tst <= (eps2 * fabsf(d[t - 1])) * fabsf(d[t - 2]) + safmin) { mm = t; break; }
          }
        }
        if (mm > lend) e[mm - 2] = 0.0f;
        float p = d[l - 1];
        if (mm == l) {
          d[l - 1] = p; --l;
          if (l >= lend) continue; break;
        }
        if (mm == l - 1) {
          float rt1, rt2, c, s;
          slaev2f(d[l - 2], e[l - 2], d[l - 1], &rt1, &rt2, &c, &s);
          for (int r2 = 0; r2 < 3; ++r2) {
            float t = Z[r2][l - 1];
            Z[r2][l - 1] = c * t - s * Z[r2][l - 2];
            Z[r2][l - 2] = s * t + c * Z[r2][l - 2];
          }
          d[l - 2] = rt1; d[l - 1] = rt2; e[l - 2] = 0.0f;
          l -= 2;
          if (l >= lend) continue; break;
        }
        if (jtot == nmaxit) break;
        ++jtot;
        float g = (d[l - 2] - p) / (2.0f * e[l - 2]);
        float r = slapy2f(g, 1.0f);
        g = d[mm - 1] - p + e[l - 2] / (g + copysignf(r, g));
        float s = 1.0f, c = 1.0f;
        p = 0.0f;
        float cw[2], sw[2];
        for (int i = mm; i <= l - 1; ++i) {
          float f = s * e[i - 1];
          float b = c * e[i - 1];
          slartgf(g, f, &c, &s, &r);
          if (i != mm) e[i - 2] = r;
          g = d[i - 1] - p;
          r = (d[i] - g) * s + 2.0f * c * b;
          p = s * r;
          d[i - 1] = g + p;
          g = c * r - b;
          cw[i - mm] = c; sw[i - mm] = s;
        }
        for (int j = mm; j <= l - 1; ++j) {
          float cc = cw[j - mm], ss = sw[j - mm];
          for (int r2 = 0; r2 < 3; ++r2) {
            float t = Z[r2][j];
            Z[r2][j]     = cc * t - ss * Z[r2][j - 1];
            Z[r2][j - 1] = ss * t + cc * Z[r2][j - 1];
          }
        }
        d[l - 1] -= p;
        e[l - 2] = g;
      }
    }
    if (iscale == 1) {
      float mul = anorm / ssfmax;
      for (int ii = lsv; ii <= lendsv; ++ii) d[ii - 1] *= mul;
      for (int ii = lsv; ii <= lendsv - 1; ++ii) e[ii - 1] *= mul;
    } else if (iscale == 2) {
      float mul = anorm / ssfmin;
      for (int ii = lsv; ii <= lendsv; ++ii) d[ii - 1] *= mul;
      for (int ii = lsv; ii <= lendsv - 1; ++ii) e[ii - 1] *= mul;
    }
    if (jtot >= nmaxit) break;
  }
  for (int ii = 2; ii <= n; ++ii) {
    int i0 = ii - 1, k0 = i0;
    float p = d[i0 - 1];
    for (int j = ii; j <= n; ++j)
      if (d[j - 1] < p) { k0 = j; p = d[j - 1]; }
    if (k0 != i0) {
      d[k0 - 1] = d[i0 - 1]; d[i0 - 1] = p;
      for (int r2 = 0; r2 < 3; ++r2) {
        float t = Z[r2][i0 - 1]; Z[r2][i0 - 1] = Z[r2][k0 - 1]; Z[r2][k0 - 1] = t;
      }
    }
  }
}

__device__ void ssytrd3(float a11, float a21, float a31, float a22, float a32, float a33,
                        float d[3], float e[2], float* tau, float* u) {
  float xnorm = fabsf(a31);
  if (xnorm == 0.0f) {
    *tau = 0.0f; *u = 0.0f;
    d[0] = a11; d[1] = a22; d[2] = a33; e[0] = a21; e[1] = a32;
    return;
  }
  float beta = -copysignf(slapy2f(a21, xnorm), a21);
  float taui = (beta - a21) / beta;
  float uu = a31 * (1.0f / (a21 - beta));
  float w1 = taui * a22 + taui * (a32 * uu);
  float w2 = taui * a32 + (taui * uu) * a33;
  float alpha = -0.5f * taui * (w1 + w2 * uu);
  w1 += alpha; w2 += alpha * uu;
  float na22 = a22 - 2.0f * w1;
  float na32 = a32 - (uu * w1 + w2);
  float na33 = a33 - 2.0f * (uu * w2);
  d[0] = a11; d[1] = na22; d[2] = na33;
  e[0] = beta; e[1] = na32;
  *tau = taui; *u = uu;
}

// ---------------- K1: kNN via 3-pass quantized radix-select ------------------------
// Key: u = trunc(clamp(dist,0,127) * 2^24) — exact pow2 scale => monotone truncation.
// Top byte = floor(dist^2) spreads histogram (fixes the fp-exponent bin pileup).
// Threshold found to 24-bit bin; equals-at-bin resolved by exact (dist,index) order.
__global__ __launch_bounds__(256) void knn_kernel(const float* __restrict__ pts, int N) {
  __shared__ unsigned skey[NPTS];
  __shared__ unsigned hist[256];
  __shared__ unsigned sred[4];
  __shared__ unsigned sbin[2];
  __shared__ int   eqi[64];
  __shared__ float eqd[64];
  __shared__ unsigned eqn[1];
  const int i = blockIdx.x;
  const int tid = threadIdx.x;
  const int lane = tid & 63, wid = tid >> 6;
  const float xi = pts[3 * i], yi = pts[3 * i + 1], zi = pts[3 * i + 2];
  const float d2i = xi * xi + yi * yi + zi * zi;
  hist[tid] = 0;
  if (tid == 0) eqn[0] = 0;
  __syncthreads();
  for (int j = tid; j < N; j += 256) {
    float xj = pts[3 * j], yj = pts[3 * j + 1], zj = pts[3 * j + 2];
    float d2j = xj * xj + yj * yj + zj * zj;
    float dot = fmaf(zi, zj, fmaf(yi, yj, xi * xj));
    float dist = (d2i - 2.0f * dot) + d2j;       // identical formula to R1/R2
    float dc = fminf(fmaxf(dist, 0.0f), 127.0f);
    unsigned u = (unsigned)(dc * 16777216.0f);   // exact *2^24 then trunc: monotone
    skey[j] = u;
    atomicAdd(&hist[u >> 24], 1u);               // fused pass-0 histogram
  }
  __syncthreads();
  unsigned prefix = 0, rank = 49;
  for (int pass = 0; pass < 3; ++pass) {
    const int shift = 24 - 8 * pass;
    if (pass) {
      const unsigned hmask = 0xFFFFFFFFu << (shift + 8);
      for (int j = tid; j < N; j += 256) {
        unsigned u = skey[j];
        if (((u ^ prefix) & hmask) == 0)
          atomicAdd(&hist[(u >> shift) & 255u], 1u);
      }
      __syncthreads();
    }
    unsigned h = hist[tid];
    unsigned c = h;
    #pragma unroll
    for (int off = 1; off < 64; off <<= 1) {
      unsigned o = __shfl_up(c, off);
      if (lane >= off) c += o;
    }
    if (lane == 63) sred[wid] = c;
    __syncthreads();
    unsigned wbase = 0;
    for (int w2 = 0; w2 < wid; ++w2) wbase += sred[w2];
    c += wbase;
    unsigned excl = c - h;
    if (rank >= excl && rank < c) { sbin[0] = (unsigned)tid; sbin[1] = rank - excl; }
    __syncthreads();
    prefix |= sbin[0] << shift;
    rank = sbin[1];
    __syncthreads();
    if (pass < 2) { hist[tid] = 0; __syncthreads(); }
  }
  const unsigned t24 = prefix;                    // low 8 bits zero
  // gather: count strict-below matches; collect equal-bin candidates w/ exact dist
  int cnt = 0;
  for (int j = tid; j < N; j += 256) {
    unsigned u = skey[j];
    if (u < t24 && j != i) {
      ++cnt;
    } else if ((u & 0xFFFFFF00u) == t24) {
      float xj = pts[3 * j], yj = pts[3 * j + 1], zj = pts[3 * j + 2];
      float d2j = xj * xj + yj * yj + zj * zj;
      float dot = fmaf(zi, zj, fmaf(yi, yj, xi * xj));
      float dist = (d2i - 2.0f * dot) + d2j;
      unsigned e = atomicAdd(&eqn[0], 1u);
      if (e < 64u) { eqi[e] = j; eqd[e] = dist; }
    }
  }
  unsigned cc = (unsigned)cnt;
  #pragma unroll
  for (int off = 1; off < 64; off <<= 1) {
    unsigned o = __shfl_up(cc, off);
    if (lane >= off) cc += o;
  }
  if (lane == 63) sred[wid] = cc;
  __syncthreads();
  unsigned wbase = 0;
  for (int w2 = 0; w2 < wid; ++w2) wbase += sred[w2];
  int base = 1 + (int)(wbase + cc - (unsigned)cnt);  // deterministic compaction slot
  for (int j = tid; j < N; j += 256) {
    unsigned u = skey[j];
    if (u < t24 && j != i) g_idx[i * KNB + (base++)] = j;
  }
  if (tid == 0) {
    g_idx[i * KNB] = i;                            // self = global min distance
    int slot = 1 + (int)(sred[0] + sred[1] + sred[2] + sred[3]);
    int need = KNB - slot;                         // >= 1
    int ne = (int)eqn[0]; if (ne > 64) ne = 64;
    for (int e2 = 0; e2 < need; ++e2) {            // exact (dist, index) ascending
      int bq = 0, bidx = 0x7FFFFFFF; float bd = 3.4e38f;
      for (int q = 0; q < ne; ++q) {
        if (eqi[q] < 0) continue;
        float dq = eqd[q];
        if (dq < bd || (dq == bd && eqi[q] < bidx)) { bd = dq; bidx = eqi[q]; bq = q; }
      }
      g_idx[i * KNB + slot + e2] = bidx;
      eqi[bq] = -1;
    }
  }
}

// ---------------- K2: frames, wave-per-point (exact R2 accumulation order) ---------
__global__ __launch_bounds__(256) void frames_kernel(const float* __restrict__ pts, int N) {
  __shared__ float sx[4][52], sy[4][52], sz[4][52];
  const int tid = threadIdx.x, lane = tid & 63, w = tid >> 6;
  const int i = blockIdx.x * 4 + w;
  const int base = i * KNB;
  if (lane < KNB) {
    int j = g_idx[base + lane];
    sx[w][lane] = pts[3 * j];
    sy[w][lane] = pts[3 * j + 1];
    sz[w][lane] = pts[3 * j + 2];
  }
  __syncthreads();
  // all lanes run the serial sums uniformly (no divergence, identical order to R2)
  float mx = 0.0f, my = 0.0f, mz = 0.0f;
  for (int kk = 0; kk < KNB; ++kk) { mx += sx[w][kk]; my += sy[w][kk]; mz += sz[w][kk]; }
  mx /= 50.0f; my /= 50.0f; mz /= 50.0f;
  float c00 = 0, c01 = 0, c02 = 0, c11 = 0, c12 = 0, c22 = 0;
  for (int kk = 0; kk < KNB; ++kk) {
    float cx = sx[w][kk] - mx, cy = sy[w][kk] - my, cz = sz[w][kk] - mz;
    c00 = fmaf(cx, cx, c00); c01 = fmaf(cx, cy, c01); c02 = fmaf(cx, cz, c02);
    c11 = fmaf(cy, cy, c11); c12 = fmaf(cy, cz, c12); c22 = fmaf(cz, cz, c22);
  }
  c00 *= 0.5f; c01 *= 0.5f; c02 *= 0.5f; c11 *= 0.5f; c12 *= 0.5f; c22 *= 0.5f;

  float d[3], e[2], tau, u;
  ssytrd3(c00, c01, c02, c11, c12, c22, d, e, &tau, &u);
  float Z[3][3];
  ssteqr3(d, e, Z);
  if (tau != 0.0f) {
    for (int c = 0; c < 3; ++c) {
      float sum = Z[1][c] + u * Z[2][c];
      Z[1][c] -= tau * sum;
      Z[2][c] -= tau * u * sum;
    }
  }
  float n0 = Z[0][0], n1 = Z[1][0], n2 = Z[2][0];
  float a0 = Z[0][1], a1 = Z[1][1], a2 = Z[2][1];
  float b0 = Z[0][2], b1 = Z[1][2], b2 = Z[2][2];
  float cxp = a1 * b2 - a2 * b1, cyp = a2 * b0 - a0 * b2, czp = a0 * b1 - a1 * b0;
  float det = n0 * cxp + n1 * cyp + n2 * czp;
  a0 *= det; a1 *= det; a2 *= det;

  const float xi = pts[3 * i], yi = pts[3 * i + 1], zi = pts[3 * i + 2];
  float dt0 = 0.0f, dt1 = 0.0f;
  float mn0 = 3.0e38f, mx0 = -3.0e38f, mn1 = 3.0e38f, mx1 = -3.0e38f;
  if (lane < KNB) {
    float dx = sx[w][lane] - xi, dy = sy[w][lane] - yi, dz = sz[w][lane] - zi;
    dt0 = dx * a0 + dy * a1 + dz * a2;
    dt1 = dx * b0 + dy * b1 + dz * b2;
    g_dt[2 * (base + lane)] = dt0;
    g_dt[2 * (base + lane) + 1] = dt1;
    mn0 = dt0; mx0 = dt0; mn1 = dt1; mx1 = dt1;
  }
  #pragma unroll
  for (int off = 32; off > 0; off >>= 1) {   // fmin/fmax exactly assoc+comm
    mn0 = fminf(mn0, __shfl_down(mn0, off));
    mx0 = fmaxf(mx0, __shfl_down(mx0, off));
    mn1 = fminf(mn1, __shfl_down(mn1, off));
    mx1 = fmaxf(mx1, __shfl_down(mx1, off));
  }
  if (lane == 0) {
    g_nrm[3 * i] = n0; g_nrm[3 * i + 1] = n1; g_nrm[3 * i + 2] = n2;
    g_t1[3 * i] = a0;  g_t1[3 * i + 1] = a1;  g_t1[3 * i + 2] = a2;
    g_t2[3 * i] = b0;  g_t2[3 * i + 1] = b1;  g_t2[3 * i + 2] = b2;
    float bmin0 = mn0 * 1.1f, bmax0 = mx0 * 1.1f;
    float bmin1 = mn1 * 1.1f, bmax1 = mx1 * 1.1f;
    float ml = fmaxf(bmax0 - bmin0, bmax1 - bmin1);
    g_bmin[2 * i] = bmin0; g_bmin[2 * i + 1] = bmin1;
    g_ml[i] = ml;
  }
}

// ---------------- K3: Voronoi counts, register-tiled (bit-identical math) ----------
// lane = column x; each lane owns 16 rows; seeds read from LDS once per seed.
__global__ __launch_bounds__(256) void voronoi_kernel(int N) {
  __shared__ float2 sc[KNB];
  __shared__ int swc[4];
  const int i = blockIdx.x;
  const int tid = threadIdx.x;
  const int lane = tid & 63, wid = tid >> 6;
  const float ml = g_ml[i];
  const float b0 = g_bmin[2 * i], b1 = g_bmin[2 * i + 1];
  if (tid < KNB) {
    float dt0 = g_dt[2 * (i * KNB + tid)];
    float dt1 = g_dt[2 * (i * KNB + tid) + 1];
    sc[tid] = make_float2((dt0 - b0) / ml * 2.0f - 1.0f,
                          (dt1 - b1) / ml * 2.0f - 1.0f);
  }
  __syncthreads();
  const float step = 2.0f / 63.0f;
  const float gx = fmaf((float)lane, step, -1.0f);
  const float2 c0 = sc[0];
  const float ex = gx - c0.x;
  float gyv[16], d0v[16], mv[16];
  #pragma unroll
  for (int r = 0; r < 16; ++r) {
    float gy = fmaf((float)(wid * 16 + r), step, -1.0f);
    gyv[r] = gy;
    float ey = gy - c0.y;
    d0v[r] = ex * ex + ey * ey;                 // same expr as R1
    mv[r] = 3.0e38f;
  }
  for (int j = 1; j < KNB; ++j) {
    float2 cc = sc[j];
    float dx = gx - cc.x;
    #pragma unroll
    for (int r = 0; r < 16; ++r) {
      float dy = gyv[r] - cc.y;
      float dd = fmaf(dx, dx, dy * dy);         // same expr as R1
      mv[r] = fminf(mv[r], dd);                 // same fmin chain order (j asc)
    }
  }
  int cnt = 0;
  #pragma unroll
  for (int r = 0; r < 16; ++r) cnt += (d0v[r] <= mv[r]) ? 1 : 0;
  #pragma unroll
  for (int off = 32; off > 0; off >>= 1) cnt += __shfl_down(cnt, off);
  if (lane == 0) swc[wid] = cnt;
  __syncthreads();
  if (tid == 0) {
    int tot = swc[0] + swc[1] + swc[2] + swc[3];
    g_va[i] = (float)tot * (ml * ml) / 3969.0f;
  }
}

// ---------------- K4: Weingarten fit, wave-per-point (exact R2 order) --------------
__global__ __launch_bounds__(256) void curv_kernel(int N) {
  __shared__ float s0[4][52], s1[4][52], tx[4][52], ty[4][52], tz[4][52];
  const int tid = threadIdx.x, lane = tid & 63, w = tid >> 6;
  const int i = blockIdx.x * 4 + w;
  const int base = i * KNB;
  if (lane < KNB) {
    int j = g_idx[base + lane];
    s0[w][lane] = g_dt[2 * (base + lane)];
    s1[w][lane] = g_dt[2 * (base + lane) + 1];
    tx[w][lane] = g_nrm[3 * j];
    ty[w][lane] = g_nrm[3 * j + 1];
    tz[w][lane] = g_nrm[3 * j + 2];
  }
  __syncthreads();
  float nx = g_nrm[3 * i], ny = g_nrm[3 * i + 1], nz = g_nrm[3 * i + 2];
  float ax = g_t1[3 * i], ay = g_t1[3 * i + 1], az = g_t1[3 * i + 2];
  float bx = g_t2[3 * i], by = g_t2[3 * i + 1], bz = g_t2[3 * i + 2];
  float xx = 0, xy = 0, yy = 0;
  float y00 = 0, y01 = 0, y10 = 0, y11 = 0;
  for (int kk = 0; kk < KNB; ++kk) {
    float dt0 = s0[w][kk], dt1 = s1[w][kk];
    float lx = tx[w][kk] - nx, ly = ty[w][kk] - ny, lz = tz[w][kk] - nz;
    float dn0 = lx * ax + ly * ay + lz * az;
    float dn1 = lx * bx + ly * by + lz * bz;
    xx = fmaf(dt0, dt0, xx); xy = fmaf(dt0, dt1, xy); yy = fmaf(dt1, dt1, yy);
    y00 = fmaf(dn0, dt0, y00); y01 = fmaf(dn0, dt1, y01);
    y10 = fmaf(dn1, dt0, y10); y11 = fmaf(dn1, dt1, y11);
  }
  float s00 = y00 + y00, s01 = y01 + y10, s11 = y11 + y11;
  float rt1, rt2, cs1, sn1;
  slaev2f(xx, xy, yy, &rt1, &rt2, &cs1, &sn1);
  float a, bb, q00, q10, q01, q11;
  if (rt1 <= rt2) { a = rt1; bb = rt2; q00 = cs1; q10 = sn1; q01 = -sn1; q11 = cs1; }
  else            { a = rt2; bb = rt1; q00 = -sn1; q10 = cs1; q01 = cs1; q11 = sn1; }
  float t00 = s00 * q00 + s01 * q10, t01 = s00 * q01 + s01 * q11;
  float t10 = s01 * q00 + s11 * q10, t11 = s01 * q01 + s11 * q11;
  float m00 = q00 * t00 + q10 * t10;
  float m01 = q00 * t01 + q10 * t11;
  float m10 = q01 * t00 + q11 * t10;
  float m11 = q01 * t01 + q11 * t11;
  float e00 = m00 / (2.0f * a + 1e-8f);
  float e01 = m01 / ((a + bb) + 1e-8f);
  float e10 = m10 / ((a + bb) + 1e-8f);
  float e11 = m11 / (2.0f * bb + 1e-8f);
  float u00 = q00 * e00 + q01 * e10, u01 = q00 * e01 + q01 * e11;
  float u10 = q10 * e00 + q11 * e10, u11 = q10 * e01 + q11 * e11;
  float w00 = u00 * q00 + u01 * q01;
  float w01 = u00 * q10 + u01 * q11;
  float w10 = u10 * q00 + u11 * q01;
  float w11 = u10 * q10 + u11 * q11;
  float gauss = w00 * w11 - w01 * w10;
  if (lane == 0) g_terms[i] = gauss * g_va[i];
}

// ---------------- K5: final reduction (unchanged — passed R1/R2) -------------------
__global__ __launch_bounds__(256) void reduce_kernel(float* __restrict__ out, int N) {
  __shared__ float sw[4];
  float s = 0.0f;
  for (int j = threadIdx.x; j < N; j += 256) s += g_terms[j];
  const int lane = threadIdx.x & 63, wid = threadIdx.x >> 6;
  #pragma unroll
  for (int off = 32; off > 0; off >>= 1) s += __shfl_down(s, off);
  if (lane == 0) sw[wid] = s;
  __syncthreads();
  if (threadIdx.x == 0) {
    float tot = sw[0] + sw[1] + sw[2] + sw[3];
    out[0] = (tot / 2.0f) / 3.14159265358979323846f;
  }
}

extern "C" void kernel_launch(void* const* d_in, const int* in_sizes, int n_in,
                              void* d_out, int out_size, void* d_ws, size_t ws_size,
                              hipStream_t stream) {
  const float* pts = (const float*)d_in[0];
  const int N = in_sizes[0] / 3;   // 4096
  knn_kernel<<<N, 256, 0, stream>>>(pts, N);
  frames_kernel<<<N / 4, 256, 0, stream>>>(pts, N);
  voronoi_kernel<<<N, 256, 0, stream>>>(N);
  curv_kernel<<<N / 4, 256, 0, stream>>>(N);
  reduce_kernel<<<1, 256, 0, stream>>>((float*)d_out, N);
}